// Round 9
// baseline (170.565 us; speedup 1.0000x reference)
//
#include <hip/hip_runtime.h>

#define B_ 16
#define N_ 1024
#define DIN 256
#define K_ 24
#define D_ 128
#define KD_ 3072
#define NCHUNK 64
#define UROW 257      /* u_lds row stride (floats); 257 keeps conflicts <=2-way */
#define EPS_ 1e-7f
#define NBLK 256
#define NUNIT 384

// sc1 (agent-scope, L2-bypass) accessors for cross-block data that is
// REWRITTEN within one execution (tpart/tupart/w2). Relaxed: no cache ops.
__device__ __forceinline__ float cl(const float* p) {
    return __hip_atomic_load(p, __ATOMIC_RELAXED, __HIP_MEMORY_SCOPE_AGENT);
}
__device__ __forceinline__ void cs(float* p, float v) {
    __hip_atomic_store(p, v, __ATOMIC_RELAXED, __HIP_MEMORY_SCOPE_AGENT);
}
__device__ __forceinline__ unsigned clu(const unsigned* p) {
    return __hip_atomic_load(p, __ATOMIC_RELAXED, __HIP_MEMORY_SCOPE_AGENT);
}
__device__ __forceinline__ void fadd(unsigned* p) {
    __hip_atomic_fetch_add(p, 1u, __ATOMIC_RELAXED, __HIP_MEMORY_SCOPE_AGENT);
}
// Per-wave release: sc1 stores ack at the coherence point, so vmcnt(0) makes
// them agent-visible; the relaxed flag add issued after is ordered behind them.
#define WAVE_DRAIN() asm volatile("s_waitcnt vmcnt(0)" ::: "memory")

// flags (u32 index): F1[j][b] (tpart/tupart iter-j ready, target 128),
// F2[j][b] (w2 iter-j ready, target 24), FW (Wt ready, target 2048)
__device__ __forceinline__ unsigned* F1p(unsigned* f, int j, int b) { return f + (j * 16 + b) * 16; }
__device__ __forceinline__ unsigned* F2p(unsigned* f, int j, int b) { return f + 768 + (j * 16 + b) * 16; }
__device__ __forceinline__ unsigned* FWp(unsigned* f) { return f + 1280; }

__device__ __forceinline__ void wait_flag(unsigned* f, unsigned tgt) {
    while (clu(f) < tgt) __builtin_amdgcn_s_sleep(2);
    asm volatile("" ::: "memory");
}

// ---- sv: one wave per (b,k) unit. NO block barriers; wave-private LDS scratch.
__device__ __forceinline__ void sv_phase(int iter, int unit, int l,
                                         const float* __restrict__ W,
                                         const float* __restrict__ Wt,
                                         const float* __restrict__ tupart,
                                         const float* __restrict__ tpart,
                                         float* __restrict__ w2,
                                         float* __restrict__ outv,
                                         float* myt, float* myv,
                                         unsigned* flg) {
    const int bp = unit / K_, k = unit % K_;
    wait_flag(F1p(flg, iter, bp), 128);
    // t-reduce: lane l owns i = l + 64c
    float tr0 = 0.f, tr1 = 0.f, tr2 = 0.f, tr3 = 0.f;
    if (iter == 0) {
        for (int s2 = 0; s2 < 16; ++s2) {
            const float* p = tupart + (size_t)(bp * 16 + s2) * 256;
            tr0 += cl(p + l); tr1 += cl(p + l + 64);
            tr2 += cl(p + l + 128); tr3 += cl(p + l + 192);
        }
        tr0 *= (1.f / 24.f); tr1 *= (1.f / 24.f); tr2 *= (1.f / 24.f); tr3 *= (1.f / 24.f);
    } else {
        for (int s2 = 0; s2 < 16; ++s2) {
            const float* p = tpart + (size_t)((bp * 16 + s2) * K_ + k) * 256;
            tr0 += cl(p + l); tr1 += cl(p + l + 64);
            tr2 += cl(p + l + 128); tr3 += cl(p + l + 192);
        }
    }
    myt[l] = tr0; myt[l + 64] = tr1; myt[l + 128] = tr2; myt[l + 192] = tr3;
    // s_d = sum_i t[i]*W[i,k*128+d]; lane owns d = l, l+64. W coalesced, t broadcast.
    float s0 = 0.f, s1 = 0.f;
    const float* Wk = W + k * D_;
    for (int j = 0; j < 64; ++j) {
        const float4 t4 = *(const float4*)(myt + 4 * j);
        const float* wr = Wk + (size_t)(4 * j) * KD_;
        s0 += t4.x * wr[l];            s1 += t4.x * wr[l + 64];
        s0 += t4.y * wr[KD_ + l];      s1 += t4.y * wr[KD_ + l + 64];
        s0 += t4.z * wr[2 * KD_ + l];  s1 += t4.z * wr[2 * KD_ + l + 64];
        s0 += t4.w * wr[3 * KD_ + l];  s1 += t4.w * wr[3 * KD_ + l + 64];
    }
    // squash
    float sq = s0 * s0 + s1 * s1;
    #pragma unroll
    for (int m = 1; m < 64; m <<= 1) sq += __shfl_xor(sq, m);
    const float inv = rsqrtf(sq + EPS_);
    const float v0 = s0 * inv, v1 = s1 * inv;
    if (iter == 2) {
        outv[(size_t)(bp * K_ + k) * D_ + l] = v0;
        outv[(size_t)(bp * K_ + k) * D_ + l + 64] = v1;
        return;
    }
    myv[l] = v0; myv[l + 64] = v1;
    if (iter == 0) wait_flag(FWp(flg), 2048);
    // w2[i] = sum_d v[d]*Wt[k*128+d][i]; lane owns i = l + 64c. Coalesced, cached.
    float w0 = 0.f, w1 = 0.f, w2a = 0.f, w3 = 0.f;
    const float* Wtk = Wt + (size_t)(k * D_) * 256;
    for (int d = 0; d < D_; d += 4) {
        const float4 v4 = *(const float4*)(myv + d);
        const float* r = Wtk + (size_t)d * 256;
        w0 += v4.x * r[l]; w1 += v4.x * r[l + 64]; w2a += v4.x * r[l + 128]; w3 += v4.x * r[l + 192];
        r += 256;
        w0 += v4.y * r[l]; w1 += v4.y * r[l + 64]; w2a += v4.y * r[l + 128]; w3 += v4.y * r[l + 192];
        r += 256;
        w0 += v4.z * r[l]; w1 += v4.z * r[l + 64]; w2a += v4.z * r[l + 128]; w3 += v4.z * r[l + 192];
        r += 256;
        w0 += v4.w * r[l]; w1 += v4.w * r[l + 64]; w2a += v4.w * r[l + 128]; w3 += v4.w * r[l + 192];
    }
    float* wp = w2 + (size_t)unit * 256;
    cs(wp + l, w0); cs(wp + l + 64, w1); cs(wp + l + 128, w2a); cs(wp + l + 192, w3);
    WAVE_DRAIN();
    if (l == 0) fadd(F2p(flg, iter, bp));
}

// ---- fused: logits + softmax + t-partials. 2 barriers total.
__device__ __forceinline__ void fused_phase(int iter, int b, int beta, int t, int l,
                                            const float* __restrict__ w2,
                                            float* __restrict__ tpart,
                                            const float* u_lds,
                                            float* w2_lds, float* c_lds,
                                            unsigned* flg) {
    wait_flag(F2p(flg, iter - 1, b), 24);
    const float* w2g = w2 + (size_t)b * K_ * DIN;
    #pragma unroll
    for (int r = 0; r < 12; ++r)
        w2_lds[r * 512 + t] = cl(w2g + r * 512 + t);
    __syncthreads();
    // logits: n = t>>3, p = t&7; i-chunks p*4 + g*32 (interleaved)
    {
        const int n = t >> 3, p = t & 7;
        float acc[K_];
        #pragma unroll
        for (int k = 0; k < K_; ++k) acc[k] = 0.f;
        #pragma unroll
        for (int g = 0; g < 8; ++g) {
            const int i0 = p * 4 + g * 32;
            const float ua0 = u_lds[n * UROW + i0];
            const float ua1 = u_lds[n * UROW + i0 + 1];
            const float ua2 = u_lds[n * UROW + i0 + 2];
            const float ua3 = u_lds[n * UROW + i0 + 3];
            #pragma unroll
            for (int k = 0; k < K_; ++k) {
                const float4 wq = *(const float4*)(w2_lds + k * DIN + i0);
                acc[k] += ua0 * wq.x + ua1 * wq.y + ua2 * wq.z + ua3 * wq.w;
            }
        }
        #pragma unroll
        for (int m = 1; m < 8; m <<= 1)
            #pragma unroll
            for (int k = 0; k < K_; ++k) acc[k] += __shfl_xor(acc[k], m);
        // softmax (redundant per lane); lane p==0 writes all 24 (STATIC indices
        // only -- runtime-indexed register arrays demote to scratch)
        float mx = acc[0];
        #pragma unroll
        for (int k = 1; k < K_; ++k) mx = fmaxf(mx, acc[k]);
        float sm = 0.f;
        #pragma unroll
        for (int k = 0; k < K_; ++k) { acc[k] = __expf(acc[k] - mx); sm += acc[k]; }
        const float cinv = 1.f / sm;
        if (p == 0) {
            #pragma unroll
            for (int k = 0; k < K_; ++k) c_lds[n * 28 + k] = acc[k] * cinv;
        }
    }
    __syncthreads();
    // t-partials: i = t&255, kh = t>>8 (12 k's each); c reads broadcast
    {
        const int i = t & 255, kh = t >> 8;
        float a[12];
        #pragma unroll
        for (int j = 0; j < 12; ++j) a[j] = 0.f;
        for (int n = 0; n < NCHUNK; ++n) {
            const float uv = u_lds[n * UROW + i];
            const float4* cr = (const float4*)(c_lds + n * 28 + kh * 12);
            const float4 c0 = cr[0], c1 = cr[1], c2 = cr[2];
            a[0] += uv * c0.x; a[1] += uv * c0.y; a[2] += uv * c0.z; a[3] += uv * c0.w;
            a[4] += uv * c1.x; a[5] += uv * c1.y; a[6] += uv * c1.z; a[7] += uv * c1.w;
            a[8] += uv * c2.x; a[9] += uv * c2.y; a[10] += uv * c2.z; a[11] += uv * c2.w;
        }
        float* tp = tpart + (size_t)(beta * K_ + kh * 12) * 256 + i;
        #pragma unroll
        for (int j = 0; j < 12; ++j) cs(tp + (size_t)j * 256, a[j]);
    }
    WAVE_DRAIN();
    if (l == 0) fadd(F1p(flg, iter, b));
}

__global__ __launch_bounds__(512, 1) void k_caps(const float* __restrict__ u,
                                                 const float* __restrict__ W,
                                                 float* __restrict__ outv,
                                                 float* __restrict__ tupart,
                                                 float* __restrict__ tpart,
                                                 float* __restrict__ w2,
                                                 float* __restrict__ Wt,
                                                 unsigned* __restrict__ flg) {
    const int beta = blockIdx.x;
    const int b = beta >> 4;
    const int t = threadIdx.x, w = t >> 6, l = t & 63;

    __shared__ float u_lds[NCHUNK * UROW];               // 65,792 B (persistent)
    __shared__ __align__(16) float w2_lds[K_ * DIN];     // 24,576 B
    __shared__ __align__(16) float c_lds[NCHUNK * 28];   //  7,168 B
    __shared__ __align__(16) float svbuf[8 * 388];       // 12,416 B (wave-private)

    // ---- P0: stage u chunk; build Wt rows; colsum -> tupart
    {
        const float4* ug = (const float4*)(u + (size_t)beta * NCHUNK * DIN);
        #pragma unroll
        for (int r = 0; r < 8; ++r) {
            const int idx = t + r * 512;
            const int n = idx >> 6, q = idx & 63;
            const float4 v = ug[n * 64 + q];
            float* dst = u_lds + n * UROW + q * 4;
            dst[0] = v.x; dst[1] = v.y; dst[2] = v.z; dst[3] = v.w;
        }
        const int o0 = beta * 12;  // this block's 12 rows of Wt
        #pragma unroll
        for (int rr = 0; rr < 6; ++rr) {
            const int row = (t >> 8) + rr * 2;
            const int i = t & 255;
            cs(Wt + (size_t)(o0 + row) * 256 + i, W[(size_t)i * KD_ + o0 + row]);
        }
        __syncthreads();
        if (t < DIN) {
            float a = 0.f;
            #pragma unroll 8
            for (int n = 0; n < NCHUNK; ++n) a += u_lds[n * UROW + t];
            cs(tupart + (size_t)beta * 256 + t, a);
        }
        WAVE_DRAIN();
        if (l == 0) { fadd(FWp(flg)); fadd(F1p(flg, 0, b)); }
    }

    float* myt = svbuf + w * 388;
    float* myv = myt + 256;
    const int unit = beta + 256 * w;             // wave 0 everywhere, wave 1 if beta<128
    const bool dosv = (w <= 1) && (unit < NUNIT);

    if (dosv) sv_phase(0, unit, l, W, Wt, tupart, tpart, w2, outv, myt, myv, flg);
    fused_phase(1, b, beta, t, l, w2, tpart, u_lds, w2_lds, c_lds, flg);
    if (dosv) sv_phase(1, unit, l, W, Wt, tupart, tpart, w2, outv, myt, myv, flg);
    fused_phase(2, b, beta, t, l, w2, tpart, u_lds, w2_lds, c_lds, flg);
    if (dosv) sv_phase(2, unit, l, W, Wt, tupart, tpart, w2, outv, myt, myv, flg);
}

extern "C" void kernel_launch(void* const* d_in, const int* in_sizes, int n_in,
                              void* d_out, int out_size, void* d_ws, size_t ws_size,
                              hipStream_t stream) {
    const float* u = (const float*)d_in[0];   // [16,1024,256]
    const float* W = (const float*)d_in[1];   // [256,3072]
    float* out = (float*)d_out;               // [16,24,128]

    char* ws = (char*)d_ws;
    float* tpart  = (float*)ws;                       // 6,291,456 B
    float* w2     = (float*)(ws + 6291456);           //   393,216 B
    float* tupart = (float*)(ws + 6684672);           //   262,144 B
    float* Wt     = (float*)(ws + 6946816);           // 3,145,728 B
    unsigned* flg = (unsigned*)(ws + 10092544);       //     8,192 B

    // zero the flags (captured into the graph, so every replay resets them)
    hipMemsetAsync(flg, 0, 8192, stream);

    void* args[] = {(void*)&u, (void*)&W, (void*)&out,
                    (void*)&tupart, (void*)&tpart, (void*)&w2,
                    (void*)&Wt, (void*)&flg};
    hipLaunchCooperativeKernel(reinterpret_cast<void*>(k_caps),
                               dim3(NBLK), dim3(512), args, 0, stream);
}